// Round 9
// baseline (81.458 us; speedup 1.0000x reference)
//
#include <hip/hip_runtime.h>

// Radon3D loss on MI355X — project the DIFFERENCE volume (radon is linear).
// Geometry (D=H=W=64, 120 angles over [0,120] deg): L=91, pad top=left=13.
//   ix(i,j) = 45*c*linj + 32 + 45*s - s*i,  iy(i,j) = 45*s*linj + 32 - 45*c + c*i
//   (unit steps in i: the 0.5*(L-1) unnormalization cancels the linspace step)
// FP8 (OCP e4m3) canvas, 8 B cells = 8-slice pack. Corner cells (ci,ci+1)
// and (+69,+70) -> 2 x ds_read2_b64 from ONE computed address.
// R4-R8 evidence: kernel is LATENCY-bound at ~1.5 waves/SIMD (LDS pipe only
// ~35% busy) -> this round doubles per-wave ILP by fusing the i-range split
// INSIDE each thread: two independent streams (i, i+46) with separate
// accumulators = 2 address chains + 4 outstanding LDS reads per iter.
// Coords shifted +1 (nonneg), clamped to [0,65]: out-of-support samples hit
// the zero border with zero weight == map_coordinates mode='constant' cval=0.
#define DD 64
#define NA 120
#define LL 91
#define PS 67
#define PSTR 69               // ODD cell stride -> conflict-free
#define NCELL (PS * PSTR)     // 4623 cells * 8 B = 37.0 KB
#define NSL 8                 // slices per block (one fp8 byte-lane each)
#define NANG 4                // angles per block
#define JT 96                 // j-lanes per angle (91 active)
#define NTHR (NANG * JT)      // 384 threads = 6 waves
#define NSP (64 / NSL)        // 8 slice groups
#define NAP (NA / NANG)       // 30 angle groups
#define NBLKS (NSP * NAP)     // 240 blocks -> every CU <=1 block, balanced

typedef float f32x2 __attribute__((ext_vector_type(2)));

static __device__ __forceinline__ void sample8(
    const uint2* __restrict__ P, float fi, float sn, float c,
    float bx1, float by1, float* __restrict__ acc)
{
    const float xs = fminf(fmaxf(fmaf(-fi, sn, bx1), 0.0f), 65.0f);
    const float ys = fminf(fmaxf(fmaf( fi, c,  by1), 0.0f), 65.0f);
    const int ix = (int)xs;              // trunc == floor (nonneg)
    const int iy = (int)ys;
    const float wx = xs - (float)ix;
    const float wy = ys - (float)iy;
    const float ux = 1.f - wx, uy = 1.f - wy;
    const float w00 = ux * uy, w01 = wx * uy;
    const float w10 = ux * wy, w11 = wx * wy;
    const int ci = iy * PSTR + ix;
    const uint2 q00 = P[ci],        q01 = P[ci + 1];         // ds_read2_b64
    const uint2 q10 = P[ci + PSTR], q11 = P[ci + PSTR + 1];  // ds_read2_b64
    f32x2 v;
    v = __builtin_amdgcn_cvt_pk_f32_fp8(q00.x, false); acc[0] = fmaf(w00, v.x, acc[0]); acc[1] = fmaf(w00, v.y, acc[1]);
    v = __builtin_amdgcn_cvt_pk_f32_fp8(q00.x, true);  acc[2] = fmaf(w00, v.x, acc[2]); acc[3] = fmaf(w00, v.y, acc[3]);
    v = __builtin_amdgcn_cvt_pk_f32_fp8(q00.y, false); acc[4] = fmaf(w00, v.x, acc[4]); acc[5] = fmaf(w00, v.y, acc[5]);
    v = __builtin_amdgcn_cvt_pk_f32_fp8(q00.y, true);  acc[6] = fmaf(w00, v.x, acc[6]); acc[7] = fmaf(w00, v.y, acc[7]);
    v = __builtin_amdgcn_cvt_pk_f32_fp8(q01.x, false); acc[0] = fmaf(w01, v.x, acc[0]); acc[1] = fmaf(w01, v.y, acc[1]);
    v = __builtin_amdgcn_cvt_pk_f32_fp8(q01.x, true);  acc[2] = fmaf(w01, v.x, acc[2]); acc[3] = fmaf(w01, v.y, acc[3]);
    v = __builtin_amdgcn_cvt_pk_f32_fp8(q01.y, false); acc[4] = fmaf(w01, v.x, acc[4]); acc[5] = fmaf(w01, v.y, acc[5]);
    v = __builtin_amdgcn_cvt_pk_f32_fp8(q01.y, true);  acc[6] = fmaf(w01, v.x, acc[6]); acc[7] = fmaf(w01, v.y, acc[7]);
    v = __builtin_amdgcn_cvt_pk_f32_fp8(q10.x, false); acc[0] = fmaf(w10, v.x, acc[0]); acc[1] = fmaf(w10, v.y, acc[1]);
    v = __builtin_amdgcn_cvt_pk_f32_fp8(q10.x, true);  acc[2] = fmaf(w10, v.x, acc[2]); acc[3] = fmaf(w10, v.y, acc[3]);
    v = __builtin_amdgcn_cvt_pk_f32_fp8(q10.y, false); acc[4] = fmaf(w10, v.x, acc[4]); acc[5] = fmaf(w10, v.y, acc[5]);
    v = __builtin_amdgcn_cvt_pk_f32_fp8(q10.y, true);  acc[6] = fmaf(w10, v.x, acc[6]); acc[7] = fmaf(w10, v.y, acc[7]);
    v = __builtin_amdgcn_cvt_pk_f32_fp8(q11.x, false); acc[0] = fmaf(w11, v.x, acc[0]); acc[1] = fmaf(w11, v.y, acc[1]);
    v = __builtin_amdgcn_cvt_pk_f32_fp8(q11.x, true);  acc[2] = fmaf(w11, v.x, acc[2]); acc[3] = fmaf(w11, v.y, acc[3]);
    v = __builtin_amdgcn_cvt_pk_f32_fp8(q11.y, false); acc[4] = fmaf(w11, v.x, acc[4]); acc[5] = fmaf(w11, v.y, acc[5]);
    v = __builtin_amdgcn_cvt_pk_f32_fp8(q11.y, true);  acc[6] = fmaf(w11, v.x, acc[6]); acc[7] = fmaf(w11, v.y, acc[7]);
}

__global__ __launch_bounds__(NTHR, 2) void radon_loss_kernel(
    const float* __restrict__ vout, const float* __restrict__ vgt,
    float* __restrict__ out)
{
    __shared__ uint2 P[NCELL];           // fp8 canvas, 37 KB
    __shared__ float wsum[NTHR / 64];

    const int bid = blockIdx.x;
    const int sp = bid / NAP;            // slice group 0..7
    const int ap = bid - sp * NAP;       // angle group 0..29
    const int s0 = sp * NSL;
    const int t = threadIdx.x;

    // 1) zero the padded canvas
    for (int idx = t; idx < NCELL; idx += NTHR)
        P[idx] = make_uint2(0u, 0u);
    __syncthreads();

    // 2) stage fp8 diffs of 8 slices: pixel (d,w) -> one 8 B cell
    for (int idx = t; idx < DD * DD; idx += NTHR) {
        const int d = idx >> 6, w = idx & 63;
        const int g = d * 4096 + s0 * 64 + w;
        float df[NSL];
        #pragma unroll
        for (int k = 0; k < NSL; ++k)
            df[k] = vout[g + 64 * k] - vgt[g + 64 * k];
        int p0 = 0, p1 = 0;
        p0 = __builtin_amdgcn_cvt_pk_fp8_f32(df[0], df[1], p0, false);
        p0 = __builtin_amdgcn_cvt_pk_fp8_f32(df[2], df[3], p0, true);
        p1 = __builtin_amdgcn_cvt_pk_fp8_f32(df[4], df[5], p1, false);
        p1 = __builtin_amdgcn_cvt_pk_fp8_f32(df[6], df[7], p1, true);
        P[(d + 1) * PSTR + (w + 1)] = make_uint2((unsigned)p0, (unsigned)p1);
    }
    __syncthreads();

    // 3) projection: thread = (angle slot, column j); TWO independent
    //    i-streams per thread (i and i+46) for latency-hiding ILP.
    const int ja = t / JT;
    const int j  = t - ja * JT;
    const int a  = ap * NANG + ja;
    const float theta = (float)a * (float)(3.14159265358979323846 * 120.0 / 119.0 / 180.0);
    const float c = cosf(theta), sn = sinf(theta);

    float val = 0.f;
    if (j < LL) {
        const float linj = fmaf((float)j, 2.0f / 90.0f, -1.0f);
        // +1 shift: coords in [0,65] after clamp; canvas row/col 0 is border
        const float bx1 = fmaf(c,  linj, 1.0f) * 45.0f - 12.0f + 45.0f * sn;
        const float by1 = fmaf(sn, linj, 1.0f) * 45.0f - 12.0f - 45.0f * c;
        float accA[8] = {0.f, 0.f, 0.f, 0.f, 0.f, 0.f, 0.f, 0.f};
        float accB[8] = {0.f, 0.f, 0.f, 0.f, 0.f, 0.f, 0.f, 0.f};
        #pragma unroll 3
        for (int i = 0; i < 45; ++i) {
            sample8(P, (float)i,        sn, c, bx1, by1, accA);  // i in [0,45)
            sample8(P, (float)(i + 46), sn, c, bx1, by1, accB);  // i in [46,91)
        }
        sample8(P, 45.0f, sn, c, bx1, by1, accA);                // i = 45
        #pragma unroll
        for (int k = 0; k < 8; ++k)
            val += fabsf(accA[k] + accB[k]);
    }

    // 4) block reduction + one scaled atomic per block
    #pragma unroll
    for (int off = 32; off > 0; off >>= 1)
        val += __shfl_down(val, off);
    const int wave = t >> 6, lane = t & 63;
    if (lane == 0) wsum[wave] = val;
    __syncthreads();
    if (t == 0) {
        float v = 0.f;
        #pragma unroll
        for (int wv = 0; wv < NTHR / 64; ++wv) v += wsum[wv];
        atomicAdd(out, v * (1.0f / (float)(NA * LL)));
    }
}

extern "C" void kernel_launch(void* const* d_in, const int* in_sizes, int n_in,
                              void* d_out, int out_size, void* d_ws, size_t ws_size,
                              hipStream_t stream) {
    const float* vout = (const float*)d_in[0];
    const float* vgt  = (const float*)d_in[1];
    float* out = (float*)d_out;

    hipMemsetAsync(out, 0, sizeof(float), stream);
    radon_loss_kernel<<<NBLKS, NTHR, 0, stream>>>(vout, vgt, out);
}